// Round 5
// baseline (456.113 us; speedup 1.0000x reference)
//
#include <hip/hip_runtime.h>
#include <hip/hip_fp16.h>
#include <math.h>

#define NSLOPE 0.2f

__device__ __forceinline__ float lrelu(float t) { return t > 0.f ? t : NSLOPE * t; }

// accumulate 8 fp16 values (packed in uint4) scaled by w into acc[8]
__device__ __forceinline__ void fma8h(float* acc, float w, const uint4& v) {
    const __half2* h2 = reinterpret_cast<const __half2*>(&v);
#pragma unroll
    for (int i = 0; i < 4; ++i) {
        float2 f = __half22float2(h2[i]);
        acc[2 * i]     = fmaf(w, f.x, acc[2 * i]);
        acc[2 * i + 1] = fmaf(w, f.y, acc[2 * i + 1]);
    }
}

// ---------------------------------------------------------------------------
// CSR build via two-level counting sort (writes coalesced; src fits in u16).
// ---------------------------------------------------------------------------
#define MAXB 5632
#define BE   8192

__global__ __launch_bounds__(256)
void bucketA_kernel(const int* __restrict__ src, const int* __restrict__ dst,
                    int* __restrict__ bcnt, int E, int Etot, int nb)
{
    __shared__ int hist[512];
    int tid = threadIdx.x;
    for (int i = tid; i < 512; i += 256) hist[i] = 0;
    __syncthreads();
    for (int e = blockIdx.x * 256 + tid; e < Etot; e += gridDim.x * 256) {
        int d = (e < E) ? dst[e] : (e - E);
        atomicAdd(&hist[d >> 7], 1);
    }
    __syncthreads();
    for (int i = tid; i < nb; i += 256) {
        int v = hist[i];
        if (v) atomicAdd(&bcnt[i], v);
    }
}

__global__ __launch_bounds__(512)
void scanBuckets_kernel(const int* __restrict__ bcnt, int* __restrict__ bbase,
                        int* __restrict__ gcur, int nb, int* __restrict__ offs,
                        int N, int total)
{
    __shared__ int tmp[512];
    int tid = threadIdx.x;
    int v = (tid < nb) ? bcnt[tid] : 0;
    tmp[tid] = v;
    __syncthreads();
    for (int off = 1; off < 512; off <<= 1) {
        int t = (tid >= off) ? tmp[tid - off] : 0;
        __syncthreads();
        tmp[tid] += t;
        __syncthreads();
    }
    if (tid < nb) {
        int e = tmp[tid] - v;
        bbase[tid] = e;
        gcur[tid] = e;
    }
    if (tid == 0) offs[N] = total;
}

__global__ __launch_bounds__(256)
void bucketB_kernel(const int* __restrict__ src, const int* __restrict__ dst,
                    int* __restrict__ gcur, unsigned* __restrict__ eout,
                    int E, int Etot, int nb)
{
    __shared__ int hist[512];
    __shared__ int res[512];
    __shared__ int lcur[512];
    int tid = threadIdx.x;
    int e0 = blockIdx.x * BE;
    int e1 = min(e0 + BE, Etot);

    for (int i = tid; i < 512; i += 256) hist[i] = 0;
    __syncthreads();
    for (int e = e0 + tid; e < e1; e += 256) {
        int d = (e < E) ? dst[e] : (e - E);
        atomicAdd(&hist[d >> 7], 1);
    }
    __syncthreads();
    for (int i = tid; i < nb; i += 256) {
        int h = hist[i];
        res[i] = h ? atomicAdd(&gcur[i], h) : 0;
        lcur[i] = 0;
    }
    __syncthreads();
    for (int e = e0 + tid; e < e1; e += 256) {
        int s, d;
        if (e < E) { s = src[e]; d = dst[e]; }
        else       { s = e - E; d = s; }
        int b = d >> 7;
        int p = res[b] + atomicAdd(&lcur[b], 1);
        eout[p] = (unsigned)s | ((unsigned)(d & 127) << 16);
    }
}

__global__ __launch_bounds__(256)
void bucketC_kernel(const unsigned* __restrict__ eout, const int* __restrict__ bbase,
                    const int* __restrict__ bcnt, unsigned short* __restrict__ csr,
                    int* __restrict__ offs, int N)
{
    __shared__ unsigned eb[MAXB];
    __shared__ unsigned short sbuf[MAXB];
    __shared__ int cnt128[128], cur128[128], sc[128];

    int b = blockIdx.x;
    int tid = threadIdx.x;
    int ebase = bbase[b];
    int ecnt = bcnt[b];
    int n0 = b << 7;
    int ncount = min(128, N - n0);

    if (tid < 128) cnt128[tid] = 0;
    for (int i = tid; i < ecnt; i += 256) eb[i] = eout[ebase + i];
    __syncthreads();
    for (int i = tid; i < ecnt; i += 256) atomicAdd(&cnt128[eb[i] >> 16], 1);
    __syncthreads();
    if (tid < 128) sc[tid] = cnt128[tid];
    __syncthreads();
    for (int off = 1; off < 128; off <<= 1) {
        int t = (tid >= off && tid < 128) ? sc[tid - off] : 0;
        __syncthreads();
        if (tid < 128) sc[tid] += t;
        __syncthreads();
    }
    if (tid < 128) {
        int excl = sc[tid] - cnt128[tid];
        cur128[tid] = excl;
        if (tid < ncount) offs[n0 + tid] = ebase + excl;
    }
    __syncthreads();
    for (int i = tid; i < ecnt; i += 256) {
        unsigned v = eb[i];
        int p = atomicAdd(&cur128[v >> 16], 1);
        sbuf[p] = (unsigned short)(v & 0xFFFFu);
    }
    __syncthreads();
    for (int i = tid; i < ecnt; i += 256) csr[ebase + i] = sbuf[i];
}

// ---------------------------------------------------------------------------
// w2s = W2 @ a_src2, w2d = W2 @ a_dst2  (tiny: one block)
// ---------------------------------------------------------------------------
__global__ __launch_bounds__(256)
void w2sd_kernel(const float* __restrict__ W2, const float* __restrict__ a_src2,
                 const float* __restrict__ a_dst2, float* __restrict__ w2s,
                 float* __restrict__ w2d)
{
    int t = threadIdx.x;
    const float* a = (t < 128) ? a_src2 : a_dst2;
    int k = t & 127;
    float acc = 0.f;
    for (int c = 0; c < 256; c += 4) {
        float4 w = *(const float4*)&W2[(size_t)k * 256 + c];
        float4 av = *(const float4*)&a[c];
        acc = fmaf(w.x, av.x, fmaf(w.y, av.y, fmaf(w.z, av.z, fmaf(w.w, av.w, acc))));
    }
    if (t < 128) w2s[k] = acc; else w2d[k] = acc;
}

// ---------------------------------------------------------------------------
// Layer-1 GEMM: h1 = x[M,128] @ W1[128,128] (fp16 out) + per-head al1 dots
// ---------------------------------------------------------------------------
__global__ __launch_bounds__(256)
void gemm1_kernel(const float* __restrict__ A, const float* __restrict__ W,
                  const float* __restrict__ a_src, const float* __restrict__ a_dst,
                  __half* __restrict__ Cout, float* __restrict__ al_src,
                  float* __restrict__ al_dst, int M)
{
    __shared__ float xsT[32][132];
    __shared__ float wl[32][132];

    int tid = threadIdx.x;
    int tx = tid & 15;
    int ty = tid >> 4;
    int R0 = blockIdx.x * 128;

    float acc[8][8];
#pragma unroll
    for (int r = 0; r < 8; ++r)
#pragma unroll
        for (int c = 0; c < 8; ++c) acc[r][c] = 0.f;

    for (int k0 = 0; k0 < 128; k0 += 32) {
        {
            int lk = tid & 31;
            int rb = tid >> 5;
#pragma unroll
            for (int p = 0; p < 16; ++p) {
                int r = p * 8 + rb;
                int row = R0 + r;
                xsT[lk][r] = (row < M) ? A[(size_t)row * 128 + k0 + lk] : 0.f;
            }
        }
        {
            int lj = tid & 127;
            int kb = tid >> 7;
#pragma unroll
            for (int p = 0; p < 16; ++p) {
                int kk = p * 2 + kb;
                wl[kk][lj] = W[(size_t)(k0 + kk) * 128 + lj];
            }
        }
        __syncthreads();
#pragma unroll 8
        for (int k = 0; k < 32; ++k) {
            float4 x0 = *(const float4*)&xsT[k][ty * 8];
            float4 x1 = *(const float4*)&xsT[k][ty * 8 + 4];
            float4 w0 = *(const float4*)&wl[k][tx * 8];
            float4 w1 = *(const float4*)&wl[k][tx * 8 + 4];
            float xv[8] = {x0.x, x0.y, x0.z, x0.w, x1.x, x1.y, x1.z, x1.w};
            float wv[8] = {w0.x, w0.y, w0.z, w0.w, w1.x, w1.y, w1.z, w1.w};
#pragma unroll
            for (int r = 0; r < 8; ++r)
#pragma unroll
                for (int c = 0; c < 8; ++c)
                    acc[r][c] = fmaf(xv[r], wv[c], acc[r][c]);
        }
        __syncthreads();
    }

#pragma unroll
    for (int r = 0; r < 8; ++r) {
        int row = R0 + ty * 8 + r;
        bool valid = (row < M);
        float ps = 0.f, pd = 0.f;
        if (valid) {
            __half2 p0 = __floats2half2_rn(acc[r][0], acc[r][1]);
            __half2 p1 = __floats2half2_rn(acc[r][2], acc[r][3]);
            __half2 p2 = __floats2half2_rn(acc[r][4], acc[r][5]);
            __half2 p3 = __floats2half2_rn(acc[r][6], acc[r][7]);
            uint4 pk = make_uint4(*(unsigned*)&p0, *(unsigned*)&p1,
                                  *(unsigned*)&p2, *(unsigned*)&p3);
            *(uint4*)&Cout[(size_t)row * 128 + tx * 8] = pk;
#pragma unroll
            for (int cc = 0; cc < 8; ++cc) {
                int col = tx * 8 + cc;
                ps = fmaf(acc[r][cc], a_src[col], ps);
                pd = fmaf(acc[r][cc], a_dst[col], pd);
            }
        }
        // heads are 32-col groups; thread's 8 cols lie in head tx>>2
        ps += __shfl_xor(ps, 1); ps += __shfl_xor(ps, 2);
        pd += __shfl_xor(pd, 1); pd += __shfl_xor(pd, 2);
        if (valid && (tx & 3) == 0) {
            int hh = tx >> 2;
            al_src[(size_t)row * 4 + hh] = ps;
            al_dst[(size_t)row * 4 + hh] = pd;
        }
    }
}

// ---------------------------------------------------------------------------
// Layer-1 aggregation (C=128 fp16, H=4). One block per dst node.
// Epilogue: relu -> hmid fp16, plus al2 dots with precomputed w2s/w2d.
// ---------------------------------------------------------------------------
#define CHUNK1 64
__global__ __launch_bounds__(256)
void agg1_kernel(const __half* __restrict__ feat, const unsigned short* __restrict__ csr_src,
                 const int* __restrict__ offs, const float* __restrict__ alS,
                 const float* __restrict__ alD, const float* __restrict__ bias,
                 const float* __restrict__ w2s, const float* __restrict__ w2d,
                 __half* __restrict__ hmid, float* __restrict__ alS2,
                 float* __restrict__ alD2)
{
    __shared__ int   s_src[CHUNK1];
    __shared__ float s_w[CHUNK1 * 4];
    __shared__ float red[8][16][16];    // [ch_sub][stream][lane] — conflict-free
    __shared__ float red_sw[16][16];

    int n = blockIdx.x;
    int tid = threadIdx.x;
    int lane = tid & 15;
    int stream = tid >> 4;
    int h = lane >> 2;

    int slot = tid >> 2;
    int sh = tid & 3;
    float aD = alD[(size_t)n * 4 + sh];

    int beg = offs[n], end = offs[n + 1];
    float acc0[8] = {0,0,0,0,0,0,0,0}, acc1[8] = {0,0,0,0,0,0,0,0};
    float sw0 = 0.f, sw1 = 0.f;
    const uint4* feat16 = (const uint4*)feat;

    for (int cb = beg; cb < end; cb += CHUNK1) {
        int cc = min(CHUNK1, end - cb);
        __syncthreads();
        if (slot < cc) {
            int s = csr_src[cb + slot];
            if (sh == 0) s_src[slot] = s;
            s_w[slot * 4 + sh] = __expf(lrelu(alS[(size_t)s * 4 + sh] + aD));
        }
        __syncthreads();
        int jj = stream;
        for (; jj + 16 < cc; jj += 32) {
            int s0 = s_src[jj], s1 = s_src[jj + 16];
            float w0 = s_w[jj * 4 + h], w1 = s_w[(jj + 16) * 4 + h];
            uint4 f0 = feat16[(size_t)s0 * 16 + lane];
            uint4 f1 = feat16[(size_t)s1 * 16 + lane];
            fma8h(acc0, w0, f0); sw0 += w0;
            fma8h(acc1, w1, f1); sw1 += w1;
        }
        if (jj < cc) {
            int s0 = s_src[jj];
            float w0 = s_w[jj * 4 + h];
            uint4 f0 = feat16[(size_t)s0 * 16 + lane];
            fma8h(acc0, w0, f0); sw0 += w0;
        }
    }

#pragma unroll
    for (int i = 0; i < 8; ++i) red[i][stream][lane] = acc0[i] + acc1[i];
    red_sw[stream][lane] = sw0 + sw1;
    __syncthreads();

    if (tid < 16) {
        float a[8] = {0,0,0,0,0,0,0,0};
        float s = 0.f;
#pragma unroll
        for (int st = 0; st < 16; ++st) {
#pragma unroll
            for (int i = 0; i < 8; ++i) a[i] += red[i][st][tid];
            s += red_sw[st][tid];
        }
        float inv = 1.f / (s + 1e-16f);
        float v[8];
#pragma unroll
        for (int i = 0; i < 8; ++i)
            v[i] = fmaxf(fmaf(a[i], inv, bias[tid * 8 + i]), 0.f);
        // hmid fp16 (8 halves = uint4)
        __half2 p0 = __floats2half2_rn(v[0], v[1]);
        __half2 p1 = __floats2half2_rn(v[2], v[3]);
        __half2 p2 = __floats2half2_rn(v[4], v[5]);
        __half2 p3 = __floats2half2_rn(v[6], v[7]);
        uint4 pk = make_uint4(*(unsigned*)&p0, *(unsigned*)&p1,
                              *(unsigned*)&p2, *(unsigned*)&p3);
        ((uint4*)hmid)[(size_t)n * 16 + tid] = pk;
        // al2 dots (fp32, pre-rounding)
        float ps = 0.f, pd = 0.f;
#pragma unroll
        for (int i = 0; i < 8; ++i) {
            ps = fmaf(v[i], w2s[tid * 8 + i], ps);
            pd = fmaf(v[i], w2d[tid * 8 + i], pd);
        }
        ps += __shfl_xor(ps, 1); ps += __shfl_xor(ps, 2);
        ps += __shfl_xor(ps, 4); ps += __shfl_xor(ps, 8);
        pd += __shfl_xor(pd, 1); pd += __shfl_xor(pd, 2);
        pd += __shfl_xor(pd, 4); pd += __shfl_xor(pd, 8);
        if (tid == 0) { alS2[n] = ps; alD2[n] = pd; }
    }
}

// ---------------------------------------------------------------------------
// Layer-2 aggregation in PRE-projection space (C=128 fp16, H=1):
// m[n] = sum_e alpha_e * hmid[src_e]  (normalized). Out fp32 [N,128].
// ---------------------------------------------------------------------------
#define CHUNK2 64
__global__ __launch_bounds__(256)
void agg2_kernel(const __half* __restrict__ feat, const unsigned short* __restrict__ csr_src,
                 const int* __restrict__ offs, const float* __restrict__ alS,
                 const float* __restrict__ alD, float* __restrict__ m)
{
    __shared__ int   s_src[CHUNK2];
    __shared__ float s_w[CHUNK2];
    __shared__ float red[8][16][16];
    __shared__ float red_sw[16][16];

    int n = blockIdx.x;
    int tid = threadIdx.x;
    int lane = tid & 15;
    int stream = tid >> 4;
    int beg = offs[n], end = offs[n + 1];
    float aD = alD[n];

    float acc0[8] = {0,0,0,0,0,0,0,0}, acc1[8] = {0,0,0,0,0,0,0,0};
    float sw0 = 0.f, sw1 = 0.f;
    const uint4* feat16 = (const uint4*)feat;

    for (int cb = beg; cb < end; cb += CHUNK2) {
        int cc = min(CHUNK2, end - cb);
        __syncthreads();
        if (tid < cc) {
            int s = csr_src[cb + tid];
            s_src[tid] = s;
            s_w[tid] = __expf(lrelu(alS[s] + aD));
        }
        __syncthreads();
        int jj = stream;
        for (; jj + 16 < cc; jj += 32) {
            int s0 = s_src[jj], s1 = s_src[jj + 16];
            float w0 = s_w[jj], w1 = s_w[jj + 16];
            uint4 f0 = feat16[(size_t)s0 * 16 + lane];
            uint4 f1 = feat16[(size_t)s1 * 16 + lane];
            fma8h(acc0, w0, f0); sw0 += w0;
            fma8h(acc1, w1, f1); sw1 += w1;
        }
        if (jj < cc) {
            int s0 = s_src[jj];
            float w0 = s_w[jj];
            uint4 f0 = feat16[(size_t)s0 * 16 + lane];
            fma8h(acc0, w0, f0); sw0 += w0;
        }
    }

#pragma unroll
    for (int i = 0; i < 8; ++i) red[i][stream][lane] = acc0[i] + acc1[i];
    red_sw[stream][lane] = sw0 + sw1;
    __syncthreads();

    if (tid < 16) {
        float a[8] = {0,0,0,0,0,0,0,0};
        float s = 0.f;
#pragma unroll
        for (int st = 0; st < 16; ++st) {
#pragma unroll
            for (int i = 0; i < 8; ++i) a[i] += red[i][st][tid];
            s += red_sw[st][tid];
        }
        float inv = 1.f / (s + 1e-16f);
        float4 o0, o1;
        o0.x = a[0] * inv; o0.y = a[1] * inv; o0.z = a[2] * inv; o0.w = a[3] * inv;
        o1.x = a[4] * inv; o1.y = a[5] * inv; o1.z = a[6] * inv; o1.w = a[7] * inv;
        ((float4*)m)[(size_t)n * 32 + tid * 2]     = o0;
        ((float4*)m)[(size_t)n * 32 + tid * 2 + 1] = o1;
    }
}

// ---------------------------------------------------------------------------
// Layer-2 GEMM: out = m[M,128] @ W2[128,256] + b2 (fp32 out)
// ---------------------------------------------------------------------------
__global__ __launch_bounds__(256)
void gemm2_kernel(const float* __restrict__ A, const float* __restrict__ W,
                  const float* __restrict__ bias, float* __restrict__ Cout, int M)
{
    __shared__ float xsT[32][132];
    __shared__ float wl[32][132];

    int tid = threadIdx.x;
    int tx = tid & 15;
    int ty = tid >> 4;
    int R0 = blockIdx.x * 128;
    int C0 = blockIdx.y * 128;

    float acc[8][8];
#pragma unroll
    for (int r = 0; r < 8; ++r)
#pragma unroll
        for (int c = 0; c < 8; ++c) acc[r][c] = 0.f;

    for (int k0 = 0; k0 < 128; k0 += 32) {
        {
            int lk = tid & 31;
            int rb = tid >> 5;
#pragma unroll
            for (int p = 0; p < 16; ++p) {
                int r = p * 8 + rb;
                int row = R0 + r;
                xsT[lk][r] = (row < M) ? A[(size_t)row * 128 + k0 + lk] : 0.f;
            }
        }
        {
            int lj = tid & 127;
            int kb = tid >> 7;
#pragma unroll
            for (int p = 0; p < 16; ++p) {
                int kk = p * 2 + kb;
                wl[kk][lj] = W[(size_t)(k0 + kk) * 256 + C0 + lj];
            }
        }
        __syncthreads();
#pragma unroll 8
        for (int k = 0; k < 32; ++k) {
            float4 x0 = *(const float4*)&xsT[k][ty * 8];
            float4 x1 = *(const float4*)&xsT[k][ty * 8 + 4];
            float4 w0 = *(const float4*)&wl[k][tx * 8];
            float4 w1 = *(const float4*)&wl[k][tx * 8 + 4];
            float xv[8] = {x0.x, x0.y, x0.z, x0.w, x1.x, x1.y, x1.z, x1.w};
            float wv[8] = {w0.x, w0.y, w0.z, w0.w, w1.x, w1.y, w1.z, w1.w};
#pragma unroll
            for (int r = 0; r < 8; ++r)
#pragma unroll
                for (int c = 0; c < 8; ++c)
                    acc[r][c] = fmaf(xv[r], wv[c], acc[r][c]);
        }
        __syncthreads();
    }

    float4 b0 = *(const float4*)&bias[C0 + tx * 8];
    float4 b1 = *(const float4*)&bias[C0 + tx * 8 + 4];
#pragma unroll
    for (int r = 0; r < 8; ++r) {
        int row = R0 + ty * 8 + r;
        if (row < M) {
            float4 s0 = make_float4(acc[r][0] + b0.x, acc[r][1] + b0.y,
                                    acc[r][2] + b0.z, acc[r][3] + b0.w);
            float4 s1 = make_float4(acc[r][4] + b1.x, acc[r][5] + b1.y,
                                    acc[r][6] + b1.z, acc[r][7] + b1.w);
            *(float4*)&Cout[(size_t)row * 256 + C0 + tx * 8] = s0;
            *(float4*)&Cout[(size_t)row * 256 + C0 + tx * 8 + 4] = s1;
        }
    }
}

// ---------------------------------------------------------------------------
extern "C" void kernel_launch(void* const* d_in, const int* in_sizes, int n_in,
                              void* d_out, int out_size, void* d_ws, size_t ws_size,
                              hipStream_t stream)
{
    const float* x      = (const float*)d_in[0];
    const int*   ei     = (const int*)d_in[1];
    const float* W1     = (const float*)d_in[2];
    const float* a_src1 = (const float*)d_in[3];
    const float* a_dst1 = (const float*)d_in[4];
    const float* b1     = (const float*)d_in[5];
    const float* W2     = (const float*)d_in[6];
    const float* a_src2 = (const float*)d_in[7];
    const float* a_dst2 = (const float*)d_in[8];
    const float* b2     = (const float*)d_in[9];

    const int N    = in_sizes[0] / 128;
    const int E    = in_sizes[1] / 2;
    const int Etot = E + N;
    const int* src = ei;
    const int* dst = ei + E;
    const int nb   = (N + 127) >> 7;

    char* ws = (char*)d_ws;
    size_t off = 0;
    auto carve = [&](size_t bytes) -> void* {
        void* p = ws + off;
        off += (bytes + 255) & ~(size_t)255;
        return p;
    };
    __half*  h1   = (__half*)carve((size_t)N * 128 * 2);
    float*   alS1 = (float*)carve((size_t)N * 4 * 4);
    float*   alD1 = (float*)carve((size_t)N * 4 * 4);
    __half*  hmid = (__half*)carve((size_t)N * 128 * 2);
    float*   mbuf = (float*)carve((size_t)N * 128 * 4);
    float*   alS2 = (float*)carve((size_t)N * 4);
    float*   alD2 = (float*)carve((size_t)N * 4);
    float*   w2s  = (float*)carve(128 * 4);
    float*   w2d  = (float*)carve(128 * 4);
    int*     offs = (int*)carve((size_t)(N + 1) * 4);
    int*     bcnt = (int*)carve(512 * 4);
    int*     bbas = (int*)carve(512 * 4);
    int*     gcur = (int*)carve(512 * 4);
    unsigned* eout = (unsigned*)carve((size_t)Etot * 4);
    unsigned short* csr = (unsigned short*)carve((size_t)Etot * 2);
    (void)ws_size; (void)n_in; (void)out_size;

    const int TB = 256;
    const int rgrid = (N + 127) / 128;

    hipMemsetAsync(bcnt, 0, 512 * 4, stream);

    // CSR build (counting sort, coalesced writes)
    bucketA_kernel<<<512, TB, 0, stream>>>(src, dst, bcnt, E, Etot, nb);
    scanBuckets_kernel<<<1, 512, 0, stream>>>(bcnt, bbas, gcur, nb, offs, N, Etot);
    bucketB_kernel<<<(Etot + BE - 1) / BE, TB, 0, stream>>>(src, dst, gcur, eout, E, Etot, nb);
    bucketC_kernel<<<nb, TB, 0, stream>>>(eout, bbas, bcnt, csr, offs, N);

    // Tiny precompute for fused al2
    w2sd_kernel<<<1, 256, 0, stream>>>(W2, a_src2, a_dst2, w2s, w2d);

    // Layer 1
    gemm1_kernel<<<rgrid, 256, 0, stream>>>(x, W1, a_src1, a_dst1, h1, alS1, alD1, N);
    agg1_kernel<<<N, 256, 0, stream>>>(h1, csr, offs, alS1, alD1, b1,
                                       w2s, w2d, hmid, alS2, alD2);

    // Layer 2: aggregate in 128-dim pre-projection space, then GEMM
    agg2_kernel<<<N, 256, 0, stream>>>(hmid, csr, offs, alS2, alD2, mbuf);
    gemm2_kernel<<<dim3(rgrid, 2), 256, 0, stream>>>(mbuf, W2, b2, (float*)d_out, N);
}

// Round 6
// 389.592 us; speedup vs baseline: 1.1707x; 1.1707x over previous
//
#include <hip/hip_runtime.h>
#include <hip/hip_fp16.h>
#include <math.h>

#define NSLOPE 0.2f

__device__ __forceinline__ float lrelu(float t) { return t > 0.f ? t : NSLOPE * t; }

// accumulate 8 fp16 values (packed in uint4) scaled by w into acc[8]
__device__ __forceinline__ void fma8h(float* acc, float w, const uint4& v) {
    const __half2* h2 = reinterpret_cast<const __half2*>(&v);
#pragma unroll
    for (int i = 0; i < 4; ++i) {
        float2 f = __half22float2(h2[i]);
        acc[2 * i]     = fmaf(w, f.x, acc[2 * i]);
        acc[2 * i + 1] = fmaf(w, f.y, acc[2 * i + 1]);
    }
}

// ---------------------------------------------------------------------------
// CSR build via two-level counting sort (writes coalesced; src fits in u16).
// ---------------------------------------------------------------------------
#define MAXB 5632
#define BE   8192

__global__ __launch_bounds__(256)
void bucketA_kernel(const int* __restrict__ src, const int* __restrict__ dst,
                    int* __restrict__ bcnt, int E, int Etot, int nb)
{
    __shared__ int hist[512];
    int tid = threadIdx.x;
    for (int i = tid; i < 512; i += 256) hist[i] = 0;
    __syncthreads();
    for (int e = blockIdx.x * 256 + tid; e < Etot; e += gridDim.x * 256) {
        int d = (e < E) ? dst[e] : (e - E);
        atomicAdd(&hist[d >> 7], 1);
    }
    __syncthreads();
    for (int i = tid; i < nb; i += 256) {
        int v = hist[i];
        if (v) atomicAdd(&bcnt[i], v);
    }
}

__global__ __launch_bounds__(512)
void scanBuckets_kernel(const int* __restrict__ bcnt, int* __restrict__ bbase,
                        int* __restrict__ gcur, int nb, int* __restrict__ offs,
                        int N, int total)
{
    __shared__ int tmp[512];
    int tid = threadIdx.x;
    int v = (tid < nb) ? bcnt[tid] : 0;
    tmp[tid] = v;
    __syncthreads();
    for (int off = 1; off < 512; off <<= 1) {
        int t = (tid >= off) ? tmp[tid - off] : 0;
        __syncthreads();
        tmp[tid] += t;
        __syncthreads();
    }
    if (tid < nb) {
        int e = tmp[tid] - v;
        bbase[tid] = e;
        gcur[tid] = e;
    }
    if (tid == 0) offs[N] = total;
}

__global__ __launch_bounds__(256)
void bucketB_kernel(const int* __restrict__ src, const int* __restrict__ dst,
                    int* __restrict__ gcur, unsigned* __restrict__ eout,
                    int E, int Etot, int nb)
{
    __shared__ int hist[512];
    __shared__ int res[512];
    __shared__ int lcur[512];
    int tid = threadIdx.x;
    int e0 = blockIdx.x * BE;
    int e1 = min(e0 + BE, Etot);

    for (int i = tid; i < 512; i += 256) hist[i] = 0;
    __syncthreads();
    for (int e = e0 + tid; e < e1; e += 256) {
        int d = (e < E) ? dst[e] : (e - E);
        atomicAdd(&hist[d >> 7], 1);
    }
    __syncthreads();
    for (int i = tid; i < nb; i += 256) {
        int h = hist[i];
        res[i] = h ? atomicAdd(&gcur[i], h) : 0;
        lcur[i] = 0;
    }
    __syncthreads();
    for (int e = e0 + tid; e < e1; e += 256) {
        int s, d;
        if (e < E) { s = src[e]; d = dst[e]; }
        else       { s = e - E; d = s; }
        int b = d >> 7;
        int p = res[b] + atomicAdd(&lcur[b], 1);
        eout[p] = (unsigned)s | ((unsigned)(d & 127) << 16);
    }
}

__global__ __launch_bounds__(256)
void bucketC_kernel(const unsigned* __restrict__ eout, const int* __restrict__ bbase,
                    const int* __restrict__ bcnt, unsigned short* __restrict__ csr,
                    int* __restrict__ offs, int N)
{
    __shared__ unsigned eb[MAXB];
    __shared__ unsigned short sbuf[MAXB];
    __shared__ int cnt128[128], cur128[128], sc[128];

    int b = blockIdx.x;
    int tid = threadIdx.x;
    int ebase = bbase[b];
    int ecnt = bcnt[b];
    int n0 = b << 7;
    int ncount = min(128, N - n0);

    if (tid < 128) cnt128[tid] = 0;
    for (int i = tid; i < ecnt; i += 256) eb[i] = eout[ebase + i];
    __syncthreads();
    for (int i = tid; i < ecnt; i += 256) atomicAdd(&cnt128[eb[i] >> 16], 1);
    __syncthreads();
    if (tid < 128) sc[tid] = cnt128[tid];
    __syncthreads();
    for (int off = 1; off < 128; off <<= 1) {
        int t = (tid >= off && tid < 128) ? sc[tid - off] : 0;
        __syncthreads();
        if (tid < 128) sc[tid] += t;
        __syncthreads();
    }
    if (tid < 128) {
        int excl = sc[tid] - cnt128[tid];
        cur128[tid] = excl;
        if (tid < ncount) offs[n0 + tid] = ebase + excl;
    }
    __syncthreads();
    for (int i = tid; i < ecnt; i += 256) {
        unsigned v = eb[i];
        int p = atomicAdd(&cur128[v >> 16], 1);
        sbuf[p] = (unsigned short)(v & 0xFFFFu);
    }
    __syncthreads();
    for (int i = tid; i < ecnt; i += 256) csr[ebase + i] = sbuf[i];
}

// ---------------------------------------------------------------------------
// w2s = W2 @ a_src2, w2d = W2 @ a_dst2  (tiny: one block)
// ---------------------------------------------------------------------------
__global__ __launch_bounds__(256)
void w2sd_kernel(const float* __restrict__ W2, const float* __restrict__ a_src2,
                 const float* __restrict__ a_dst2, float* __restrict__ w2s,
                 float* __restrict__ w2d)
{
    int t = threadIdx.x;
    const float* a = (t < 128) ? a_src2 : a_dst2;
    int k = t & 127;
    float acc = 0.f;
    for (int c = 0; c < 256; c += 4) {
        float4 w = *(const float4*)&W2[(size_t)k * 256 + c];
        float4 av = *(const float4*)&a[c];
        acc = fmaf(w.x, av.x, fmaf(w.y, av.y, fmaf(w.z, av.z, fmaf(w.w, av.w, acc))));
    }
    if (t < 128) w2s[k] = acc; else w2d[k] = acc;
}

// ---------------------------------------------------------------------------
// Layer-1 GEMM: h1 = x[M,128] @ W1[128,128] (fp16 out) + per-head al1 dots
// ---------------------------------------------------------------------------
__global__ __launch_bounds__(256)
void gemm1_kernel(const float* __restrict__ A, const float* __restrict__ W,
                  const float* __restrict__ a_src, const float* __restrict__ a_dst,
                  __half* __restrict__ Cout, float* __restrict__ al_src,
                  float* __restrict__ al_dst, int M)
{
    __shared__ float xsT[32][132];
    __shared__ float wl[32][132];

    int tid = threadIdx.x;
    int tx = tid & 15;
    int ty = tid >> 4;
    int R0 = blockIdx.x * 128;

    float acc[8][8];
#pragma unroll
    for (int r = 0; r < 8; ++r)
#pragma unroll
        for (int c = 0; c < 8; ++c) acc[r][c] = 0.f;

    for (int k0 = 0; k0 < 128; k0 += 32) {
        {
            int lk = tid & 31;
            int rb = tid >> 5;
#pragma unroll
            for (int p = 0; p < 16; ++p) {
                int r = p * 8 + rb;
                int row = R0 + r;
                xsT[lk][r] = (row < M) ? A[(size_t)row * 128 + k0 + lk] : 0.f;
            }
        }
        {
            int lj = tid & 127;
            int kb = tid >> 7;
#pragma unroll
            for (int p = 0; p < 16; ++p) {
                int kk = p * 2 + kb;
                wl[kk][lj] = W[(size_t)(k0 + kk) * 128 + lj];
            }
        }
        __syncthreads();
#pragma unroll 8
        for (int k = 0; k < 32; ++k) {
            float4 x0 = *(const float4*)&xsT[k][ty * 8];
            float4 x1 = *(const float4*)&xsT[k][ty * 8 + 4];
            float4 w0 = *(const float4*)&wl[k][tx * 8];
            float4 w1 = *(const float4*)&wl[k][tx * 8 + 4];
            float xv[8] = {x0.x, x0.y, x0.z, x0.w, x1.x, x1.y, x1.z, x1.w};
            float wv[8] = {w0.x, w0.y, w0.z, w0.w, w1.x, w1.y, w1.z, w1.w};
#pragma unroll
            for (int r = 0; r < 8; ++r)
#pragma unroll
                for (int c = 0; c < 8; ++c)
                    acc[r][c] = fmaf(xv[r], wv[c], acc[r][c]);
        }
        __syncthreads();
    }

#pragma unroll
    for (int r = 0; r < 8; ++r) {
        int row = R0 + ty * 8 + r;
        bool valid = (row < M);
        float ps = 0.f, pd = 0.f;
        if (valid) {
            __half2 p0 = __floats2half2_rn(acc[r][0], acc[r][1]);
            __half2 p1 = __floats2half2_rn(acc[r][2], acc[r][3]);
            __half2 p2 = __floats2half2_rn(acc[r][4], acc[r][5]);
            __half2 p3 = __floats2half2_rn(acc[r][6], acc[r][7]);
            uint4 pk = make_uint4(*(unsigned*)&p0, *(unsigned*)&p1,
                                  *(unsigned*)&p2, *(unsigned*)&p3);
            *(uint4*)&Cout[(size_t)row * 128 + tx * 8] = pk;
#pragma unroll
            for (int cc = 0; cc < 8; ++cc) {
                int col = tx * 8 + cc;
                ps = fmaf(acc[r][cc], a_src[col], ps);
                pd = fmaf(acc[r][cc], a_dst[col], pd);
            }
        }
        ps += __shfl_xor(ps, 1); ps += __shfl_xor(ps, 2);
        pd += __shfl_xor(pd, 1); pd += __shfl_xor(pd, 2);
        if (valid && (tx & 3) == 0) {
            int hh = tx >> 2;
            al_src[(size_t)row * 4 + hh] = ps;
            al_dst[(size_t)row * 4 + hh] = pd;
        }
    }
}

// ---------------------------------------------------------------------------
// Layer-1 aggregation, WAVE-PER-NODE (C=128 fp16, H=4). No LDS, no barriers.
// Wave: 16 channel-lanes (8 ch each) x 4 edge slots; shfl reductions.
// Epilogue: relu -> hmid fp16, plus al2 dots with precomputed w2s/w2d.
// ---------------------------------------------------------------------------
__global__ __launch_bounds__(256)
void agg1_kernel(const __half* __restrict__ feat, const unsigned short* __restrict__ csr_src,
                 const int* __restrict__ offs, const float* __restrict__ alS,
                 const float* __restrict__ alD, const float* __restrict__ bias,
                 const float* __restrict__ w2s, const float* __restrict__ w2d,
                 __half* __restrict__ hmid, float* __restrict__ alS2,
                 float* __restrict__ alD2, int N)
{
    int lane = threadIdx.x & 63;
    int n = blockIdx.x * 4 + (threadIdx.x >> 6);
    if (n >= N) return;

    int lc = lane & 15;      // channel group: channels lc*8 .. lc*8+7
    int es = lane >> 4;      // edge slot 0..3
    int h = lc >> 2;         // head of this lane's channels

    float aD = alD[(size_t)n * 4 + h];
    int beg = offs[n], end = offs[n + 1];

    float acc0[8] = {0,0,0,0,0,0,0,0}, acc1[8] = {0,0,0,0,0,0,0,0};
    float sw0 = 0.f, sw1 = 0.f;
    const uint4* feat16 = (const uint4*)feat;

    int j = beg + es;
    for (; j + 4 < end; j += 8) {
        int s0 = csr_src[j];
        int s1 = csr_src[j + 4];
        float w0 = __expf(lrelu(alS[(size_t)s0 * 4 + h] + aD));
        float w1 = __expf(lrelu(alS[(size_t)s1 * 4 + h] + aD));
        uint4 f0 = feat16[(size_t)s0 * 16 + lc];
        uint4 f1 = feat16[(size_t)s1 * 16 + lc];
        fma8h(acc0, w0, f0); sw0 += w0;
        fma8h(acc1, w1, f1); sw1 += w1;
    }
    if (j < end) {
        int s0 = csr_src[j];
        float w0 = __expf(lrelu(alS[(size_t)s0 * 4 + h] + aD));
        uint4 f0 = feat16[(size_t)s0 * 16 + lc];
        fma8h(acc0, w0, f0); sw0 += w0;
    }

    float sw = sw0 + sw1;
    sw += __shfl_xor(sw, 16); sw += __shfl_xor(sw, 32);
#pragma unroll
    for (int i = 0; i < 8; ++i) {
        acc0[i] += acc1[i];
        acc0[i] += __shfl_xor(acc0[i], 16);
        acc0[i] += __shfl_xor(acc0[i], 32);
    }

    if (lane < 16) {
        float inv = 1.f / (sw + 1e-16f);
        float v[8];
#pragma unroll
        for (int i = 0; i < 8; ++i)
            v[i] = fmaxf(fmaf(acc0[i], inv, bias[lc * 8 + i]), 0.f);
        __half2 p0 = __floats2half2_rn(v[0], v[1]);
        __half2 p1 = __floats2half2_rn(v[2], v[3]);
        __half2 p2 = __floats2half2_rn(v[4], v[5]);
        __half2 p3 = __floats2half2_rn(v[6], v[7]);
        uint4 pk = make_uint4(*(unsigned*)&p0, *(unsigned*)&p1,
                              *(unsigned*)&p2, *(unsigned*)&p3);
        ((uint4*)hmid)[(size_t)n * 16 + lc] = pk;
        float ps = 0.f, pd = 0.f;
#pragma unroll
        for (int i = 0; i < 8; ++i) {
            ps = fmaf(v[i], w2s[lc * 8 + i], ps);
            pd = fmaf(v[i], w2d[lc * 8 + i], pd);
        }
        ps += __shfl_xor(ps, 1); ps += __shfl_xor(ps, 2);
        ps += __shfl_xor(ps, 4); ps += __shfl_xor(ps, 8);
        pd += __shfl_xor(pd, 1); pd += __shfl_xor(pd, 2);
        pd += __shfl_xor(pd, 4); pd += __shfl_xor(pd, 8);
        if (lane == 0) { alS2[n] = ps; alD2[n] = pd; }
    }
}

// ---------------------------------------------------------------------------
// Layer-2 aggregation, WAVE-PER-NODE, pre-projection space (C=128 fp16, H=1):
// m[n] = (sum_e w_e * hmid[src_e]) / sum_e w_e. Out fp32 [N,128].
// ---------------------------------------------------------------------------
__global__ __launch_bounds__(256)
void agg2_kernel(const __half* __restrict__ feat, const unsigned short* __restrict__ csr_src,
                 const int* __restrict__ offs, const float* __restrict__ alS,
                 const float* __restrict__ alD, float* __restrict__ m, int N)
{
    int lane = threadIdx.x & 63;
    int n = blockIdx.x * 4 + (threadIdx.x >> 6);
    if (n >= N) return;

    int lc = lane & 15;
    int es = lane >> 4;

    float aD = alD[n];
    int beg = offs[n], end = offs[n + 1];

    float acc0[8] = {0,0,0,0,0,0,0,0}, acc1[8] = {0,0,0,0,0,0,0,0};
    float sw0 = 0.f, sw1 = 0.f;
    const uint4* feat16 = (const uint4*)feat;

    int j = beg + es;
    for (; j + 4 < end; j += 8) {
        int s0 = csr_src[j];
        int s1 = csr_src[j + 4];
        float w0 = __expf(lrelu(alS[s0] + aD));
        float w1 = __expf(lrelu(alS[s1] + aD));
        uint4 f0 = feat16[(size_t)s0 * 16 + lc];
        uint4 f1 = feat16[(size_t)s1 * 16 + lc];
        fma8h(acc0, w0, f0); sw0 += w0;
        fma8h(acc1, w1, f1); sw1 += w1;
    }
    if (j < end) {
        int s0 = csr_src[j];
        float w0 = __expf(lrelu(alS[s0] + aD));
        uint4 f0 = feat16[(size_t)s0 * 16 + lc];
        fma8h(acc0, w0, f0); sw0 += w0;
    }

    float sw = sw0 + sw1;
    sw += __shfl_xor(sw, 16); sw += __shfl_xor(sw, 32);
#pragma unroll
    for (int i = 0; i < 8; ++i) {
        acc0[i] += acc1[i];
        acc0[i] += __shfl_xor(acc0[i], 16);
        acc0[i] += __shfl_xor(acc0[i], 32);
    }

    if (lane < 16) {
        float inv = 1.f / (sw + 1e-16f);
        float4 o0, o1;
        o0.x = acc0[0] * inv; o0.y = acc0[1] * inv;
        o0.z = acc0[2] * inv; o0.w = acc0[3] * inv;
        o1.x = acc0[4] * inv; o1.y = acc0[5] * inv;
        o1.z = acc0[6] * inv; o1.w = acc0[7] * inv;
        ((float4*)m)[(size_t)n * 32 + lc * 2]     = o0;
        ((float4*)m)[(size_t)n * 32 + lc * 2 + 1] = o1;
    }
}

// ---------------------------------------------------------------------------
// Layer-2 GEMM: out = m[M,128] @ W2[128,256] + b2 (fp32 out)
// ---------------------------------------------------------------------------
__global__ __launch_bounds__(256)
void gemm2_kernel(const float* __restrict__ A, const float* __restrict__ W,
                  const float* __restrict__ bias, float* __restrict__ Cout, int M)
{
    __shared__ float xsT[32][132];
    __shared__ float wl[32][132];

    int tid = threadIdx.x;
    int tx = tid & 15;
    int ty = tid >> 4;
    int R0 = blockIdx.x * 128;
    int C0 = blockIdx.y * 128;

    float acc[8][8];
#pragma unroll
    for (int r = 0; r < 8; ++r)
#pragma unroll
        for (int c = 0; c < 8; ++c) acc[r][c] = 0.f;

    for (int k0 = 0; k0 < 128; k0 += 32) {
        {
            int lk = tid & 31;
            int rb = tid >> 5;
#pragma unroll
            for (int p = 0; p < 16; ++p) {
                int r = p * 8 + rb;
                int row = R0 + r;
                xsT[lk][r] = (row < M) ? A[(size_t)row * 128 + k0 + lk] : 0.f;
            }
        }
        {
            int lj = tid & 127;
            int kb = tid >> 7;
#pragma unroll
            for (int p = 0; p < 16; ++p) {
                int kk = p * 2 + kb;
                wl[kk][lj] = W[(size_t)(k0 + kk) * 256 + C0 + lj];
            }
        }
        __syncthreads();
#pragma unroll 8
        for (int k = 0; k < 32; ++k) {
            float4 x0 = *(const float4*)&xsT[k][ty * 8];
            float4 x1 = *(const float4*)&xsT[k][ty * 8 + 4];
            float4 w0 = *(const float4*)&wl[k][tx * 8];
            float4 w1 = *(const float4*)&wl[k][tx * 8 + 4];
            float xv[8] = {x0.x, x0.y, x0.z, x0.w, x1.x, x1.y, x1.z, x1.w};
            float wv[8] = {w0.x, w0.y, w0.z, w0.w, w1.x, w1.y, w1.z, w1.w};
#pragma unroll
            for (int r = 0; r < 8; ++r)
#pragma unroll
                for (int c = 0; c < 8; ++c)
                    acc[r][c] = fmaf(xv[r], wv[c], acc[r][c]);
        }
        __syncthreads();
    }

    float4 b0 = *(const float4*)&bias[C0 + tx * 8];
    float4 b1 = *(const float4*)&bias[C0 + tx * 8 + 4];
#pragma unroll
    for (int r = 0; r < 8; ++r) {
        int row = R0 + ty * 8 + r;
        if (row < M) {
            float4 s0 = make_float4(acc[r][0] + b0.x, acc[r][1] + b0.y,
                                    acc[r][2] + b0.z, acc[r][3] + b0.w);
            float4 s1 = make_float4(acc[r][4] + b1.x, acc[r][5] + b1.y,
                                    acc[r][6] + b1.z, acc[r][7] + b1.w);
            *(float4*)&Cout[(size_t)row * 256 + C0 + tx * 8] = s0;
            *(float4*)&Cout[(size_t)row * 256 + C0 + tx * 8 + 4] = s1;
        }
    }
}

// ---------------------------------------------------------------------------
extern "C" void kernel_launch(void* const* d_in, const int* in_sizes, int n_in,
                              void* d_out, int out_size, void* d_ws, size_t ws_size,
                              hipStream_t stream)
{
    const float* x      = (const float*)d_in[0];
    const int*   ei     = (const int*)d_in[1];
    const float* W1     = (const float*)d_in[2];
    const float* a_src1 = (const float*)d_in[3];
    const float* a_dst1 = (const float*)d_in[4];
    const float* b1     = (const float*)d_in[5];
    const float* W2     = (const float*)d_in[6];
    const float* a_src2 = (const float*)d_in[7];
    const float* a_dst2 = (const float*)d_in[8];
    const float* b2     = (const float*)d_in[9];

    const int N    = in_sizes[0] / 128;
    const int E    = in_sizes[1] / 2;
    const int Etot = E + N;
    const int* src = ei;
    const int* dst = ei + E;
    const int nb   = (N + 127) >> 7;

    char* ws = (char*)d_ws;
    size_t off = 0;
    auto carve = [&](size_t bytes) -> void* {
        void* p = ws + off;
        off += (bytes + 255) & ~(size_t)255;
        return p;
    };
    __half*  h1   = (__half*)carve((size_t)N * 128 * 2);
    float*   alS1 = (float*)carve((size_t)N * 4 * 4);
    float*   alD1 = (float*)carve((size_t)N * 4 * 4);
    __half*  hmid = (__half*)carve((size_t)N * 128 * 2);
    float*   mbuf = (float*)carve((size_t)N * 128 * 4);
    float*   alS2 = (float*)carve((size_t)N * 4);
    float*   alD2 = (float*)carve((size_t)N * 4);
    float*   w2s  = (float*)carve(128 * 4);
    float*   w2d  = (float*)carve(128 * 4);
    int*     offs = (int*)carve((size_t)(N + 1) * 4);
    int*     bcnt = (int*)carve(512 * 4);
    int*     bbas = (int*)carve(512 * 4);
    int*     gcur = (int*)carve(512 * 4);
    unsigned* eout = (unsigned*)carve((size_t)Etot * 4);
    unsigned short* csr = (unsigned short*)carve((size_t)Etot * 2);
    (void)ws_size; (void)n_in; (void)out_size;

    const int TB = 256;
    const int rgrid = (N + 127) / 128;
    const int agrid = (N + 3) / 4;   // 4 nodes per 256-thr block (wave-per-node)

    hipMemsetAsync(bcnt, 0, 512 * 4, stream);

    // CSR build (counting sort, coalesced writes)
    bucketA_kernel<<<512, TB, 0, stream>>>(src, dst, bcnt, E, Etot, nb);
    scanBuckets_kernel<<<1, 512, 0, stream>>>(bcnt, bbas, gcur, nb, offs, N, Etot);
    bucketB_kernel<<<(Etot + BE - 1) / BE, TB, 0, stream>>>(src, dst, gcur, eout, E, Etot, nb);
    bucketC_kernel<<<nb, TB, 0, stream>>>(eout, bbas, bcnt, csr, offs, N);

    // Tiny precompute for fused al2
    w2sd_kernel<<<1, 256, 0, stream>>>(W2, a_src2, a_dst2, w2s, w2d);

    // Layer 1
    gemm1_kernel<<<rgrid, 256, 0, stream>>>(x, W1, a_src1, a_dst1, h1, alS1, alD1, N);
    agg1_kernel<<<agrid, 256, 0, stream>>>(h1, csr, offs, alS1, alD1, b1,
                                           w2s, w2d, hmid, alS2, alD2, N);

    // Layer 2: aggregate in 128-dim pre-projection space, then GEMM
    agg2_kernel<<<agrid, 256, 0, stream>>>(hmid, csr, offs, alS2, alD2, mbuf, N);
    gemm2_kernel<<<dim3(rgrid, 2), 256, 0, stream>>>(mbuf, W2, b2, (float*)d_out, N);
}

// Round 7
// 330.792 us; speedup vs baseline: 1.3788x; 1.1778x over previous
//
#include <hip/hip_runtime.h>
#include <hip/hip_fp16.h>
#include <math.h>

#define NSLOPE 0.2f

typedef _Float16 half8 __attribute__((ext_vector_type(8)));
typedef float floatx4 __attribute__((ext_vector_type(4)));

__device__ __forceinline__ float lrelu(float t) { return t > 0.f ? t : NSLOPE * t; }

// accumulate 8 fp16 values (packed in uint4) scaled by w into acc[8]
__device__ __forceinline__ void fma8h(float* acc, float w, const uint4& v) {
    const __half2* h2 = reinterpret_cast<const __half2*>(&v);
#pragma unroll
    for (int i = 0; i < 4; ++i) {
        float2 f = __half22float2(h2[i]);
        acc[2 * i]     = fmaf(w, f.x, acc[2 * i]);
        acc[2 * i + 1] = fmaf(w, f.y, acc[2 * i + 1]);
    }
}

// ---------------------------------------------------------------------------
// CSR build via two-level counting sort (writes coalesced; src fits in u16).
// ---------------------------------------------------------------------------
#define MAXB 5632
#define BE   8192

__global__ __launch_bounds__(256)
void bucketA_kernel(const int* __restrict__ src, const int* __restrict__ dst,
                    int* __restrict__ bcnt, int E, int Etot, int nb)
{
    __shared__ int hist[512];
    int tid = threadIdx.x;
    for (int i = tid; i < 512; i += 256) hist[i] = 0;
    __syncthreads();
    for (int e = blockIdx.x * 256 + tid; e < Etot; e += gridDim.x * 256) {
        int d = (e < E) ? dst[e] : (e - E);
        atomicAdd(&hist[d >> 7], 1);
    }
    __syncthreads();
    for (int i = tid; i < nb; i += 256) {
        int v = hist[i];
        if (v) atomicAdd(&bcnt[i], v);
    }
}

__global__ __launch_bounds__(512)
void scanBuckets_kernel(const int* __restrict__ bcnt, int* __restrict__ bbase,
                        int* __restrict__ gcur, int nb, int* __restrict__ offs,
                        int N, int total)
{
    __shared__ int tmp[512];
    int tid = threadIdx.x;
    int v = (tid < nb) ? bcnt[tid] : 0;
    tmp[tid] = v;
    __syncthreads();
    for (int off = 1; off < 512; off <<= 1) {
        int t = (tid >= off) ? tmp[tid - off] : 0;
        __syncthreads();
        tmp[tid] += t;
        __syncthreads();
    }
    if (tid < nb) {
        int e = tmp[tid] - v;
        bbase[tid] = e;
        gcur[tid] = e;
    }
    if (tid == 0) offs[N] = total;
}

__global__ __launch_bounds__(256)
void bucketB_kernel(const int* __restrict__ src, const int* __restrict__ dst,
                    int* __restrict__ gcur, unsigned* __restrict__ eout,
                    int E, int Etot, int nb)
{
    __shared__ int hist[512];
    __shared__ int res[512];
    __shared__ int lcur[512];
    int tid = threadIdx.x;
    int e0 = blockIdx.x * BE;
    int e1 = min(e0 + BE, Etot);

    for (int i = tid; i < 512; i += 256) hist[i] = 0;
    __syncthreads();
    for (int e = e0 + tid; e < e1; e += 256) {
        int d = (e < E) ? dst[e] : (e - E);
        atomicAdd(&hist[d >> 7], 1);
    }
    __syncthreads();
    for (int i = tid; i < nb; i += 256) {
        int h = hist[i];
        res[i] = h ? atomicAdd(&gcur[i], h) : 0;
        lcur[i] = 0;
    }
    __syncthreads();
    for (int e = e0 + tid; e < e1; e += 256) {
        int s, d;
        if (e < E) { s = src[e]; d = dst[e]; }
        else       { s = e - E; d = s; }
        int b = d >> 7;
        int p = res[b] + atomicAdd(&lcur[b], 1);
        eout[p] = (unsigned)s | ((unsigned)(d & 127) << 16);
    }
}

__global__ __launch_bounds__(256)
void bucketC_kernel(const unsigned* __restrict__ eout, const int* __restrict__ bbase,
                    const int* __restrict__ bcnt, unsigned short* __restrict__ csr,
                    int* __restrict__ offs, int N)
{
    __shared__ unsigned eb[MAXB];
    __shared__ unsigned short sbuf[MAXB];
    __shared__ int cnt128[128], cur128[128], sc[128];

    int b = blockIdx.x;
    int tid = threadIdx.x;
    int ebase = bbase[b];
    int ecnt = bcnt[b];
    int n0 = b << 7;
    int ncount = min(128, N - n0);

    if (tid < 128) cnt128[tid] = 0;
    for (int i = tid; i < ecnt; i += 256) eb[i] = eout[ebase + i];
    __syncthreads();
    for (int i = tid; i < ecnt; i += 256) atomicAdd(&cnt128[eb[i] >> 16], 1);
    __syncthreads();
    if (tid < 128) sc[tid] = cnt128[tid];
    __syncthreads();
    for (int off = 1; off < 128; off <<= 1) {
        int t = (tid >= off && tid < 128) ? sc[tid - off] : 0;
        __syncthreads();
        if (tid < 128) sc[tid] += t;
        __syncthreads();
    }
    if (tid < 128) {
        int excl = sc[tid] - cnt128[tid];
        cur128[tid] = excl;
        if (tid < ncount) offs[n0 + tid] = ebase + excl;
    }
    __syncthreads();
    for (int i = tid; i < ecnt; i += 256) {
        unsigned v = eb[i];
        int p = atomicAdd(&cur128[v >> 16], 1);
        sbuf[p] = (unsigned short)(v & 0xFFFFu);
    }
    __syncthreads();
    for (int i = tid; i < ecnt; i += 256) csr[ebase + i] = sbuf[i];
}

// ---------------------------------------------------------------------------
// Small precompute kernels
// ---------------------------------------------------------------------------
__global__ __launch_bounds__(256)
void w2sd_kernel(const float* __restrict__ W2, const float* __restrict__ a_src2,
                 const float* __restrict__ a_dst2, float* __restrict__ w2s,
                 float* __restrict__ w2d)
{
    int t = threadIdx.x;
    const float* a = (t < 128) ? a_src2 : a_dst2;
    int k = t & 127;
    float acc = 0.f;
    for (int c = 0; c < 256; c += 4) {
        float4 w = *(const float4*)&W2[(size_t)k * 256 + c];
        float4 av = *(const float4*)&a[c];
        acc = fmaf(w.x, av.x, fmaf(w.y, av.y, fmaf(w.z, av.z, fmaf(w.w, av.w, acc))));
    }
    if (t < 128) w2s[k] = acc; else w2d[k] = acc;
}

// cast fp32 -> fp16, 4 elems/thread (n % 4 == 0)
__global__ __launch_bounds__(256)
void cast_f2h_kernel(const float* __restrict__ in, __half* __restrict__ out, int n)
{
    int i = (blockIdx.x * 256 + threadIdx.x) * 4;
    if (i >= n) return;
    float4 v = *(const float4*)&in[i];
    __half2 a = __floats2half2_rn(v.x, v.y);
    __half2 b = __floats2half2_rn(v.z, v.w);
    *(uint2*)&out[i] = make_uint2(*(unsigned*)&a, *(unsigned*)&b);
}

// WT[c][k] = (half)W[k][c]; K=128 rows, C cols. grid = C blocks x 128 thr.
__global__ __launch_bounds__(128)
void transposeW_kernel(const float* __restrict__ W, __half* __restrict__ WT, int C)
{
    int c = blockIdx.x;
    int k = threadIdx.x;
    WT[(size_t)c * 128 + k] = __float2half(W[(size_t)k * C + c]);
}

// ---------------------------------------------------------------------------
// Layer-1 GEMM (MFMA): h1 = x16[M,128] @ W1 (fp16, via W1T[128,128]) + al1 dots
// Block: 4 waves; wave (w>>1) handles rows r0+(w>>1)*16, cols (w&1)*64..+63.
// Frag layouts (m89/m92/m120-verified): A[m=lane&15][k=quad*8+j] contiguous;
// B from BT (NxK row-major) same pattern; D col=lane&15, row=quad*4+reg.
// ---------------------------------------------------------------------------
__global__ __launch_bounds__(256)
void gemm1_mfma(const __half* __restrict__ A16, const __half* __restrict__ W1T,
                const float* __restrict__ a_src, const float* __restrict__ a_dst,
                __half* __restrict__ h1, float* __restrict__ al_src,
                float* __restrict__ al_dst, int M)
{
    int wave = threadIdx.x >> 6, lane = threadIdx.x & 63;
    int lr = lane & 15, q = lane >> 4;
    int r0 = blockIdx.x * 32 + (wave >> 1) * 16;
    int wcol = (wave & 1) * 64;

    int arow = min(r0 + lr, M - 1);
    const uint4* Arow = (const uint4*)A16 + (size_t)arow * 16;
    half8 a[4];
#pragma unroll
    for (int kb = 0; kb < 4; ++kb) {
        union { uint4 u; half8 h; } c;
        c.u = Arow[kb * 4 + q];
        a[kb] = c.h;
    }

    floatx4 acc[4];
    const floatx4 zero = {0.f, 0.f, 0.f, 0.f};
#pragma unroll
    for (int ct = 0; ct < 4; ++ct) acc[ct] = zero;

#pragma unroll
    for (int ct = 0; ct < 4; ++ct) {
        const uint4* Brow = (const uint4*)W1T + (size_t)(wcol + ct * 16 + lr) * 16;
#pragma unroll
        for (int kb = 0; kb < 4; ++kb) {
            union { uint4 u; half8 h; } c;
            c.u = Brow[kb * 4 + q];
            acc[ct] = __builtin_amdgcn_mfma_f32_16x16x32_f16(a[kb], c.h, acc[ct], 0, 0, 0);
        }
    }

    // store h1 fp16
#pragma unroll
    for (int ct = 0; ct < 4; ++ct) {
        int col = wcol + ct * 16 + lr;
#pragma unroll
        for (int r = 0; r < 4; ++r) {
            int row = r0 + q * 4 + r;
            if (row < M) h1[(size_t)row * 128 + col] = __float2half(acc[ct][r]);
        }
    }

    // al1 dots: cols wcol..wcol+31 -> head hb, wcol+32..63 -> head hb+1
    float as[4], ad[4];
#pragma unroll
    for (int ct = 0; ct < 4; ++ct) {
        int col = wcol + ct * 16 + lr;
        as[ct] = a_src[col];
        ad[ct] = a_dst[col];
    }
    int hb = wcol >> 5;
#pragma unroll
    for (int r = 0; r < 4; ++r) {
        float psA = acc[0][r] * as[0] + acc[1][r] * as[1];
        float psB = acc[2][r] * as[2] + acc[3][r] * as[3];
        float pdA = acc[0][r] * ad[0] + acc[1][r] * ad[1];
        float pdB = acc[2][r] * ad[2] + acc[3][r] * ad[3];
#pragma unroll
        for (int off = 1; off < 16; off <<= 1) {
            psA += __shfl_xor(psA, off); psB += __shfl_xor(psB, off);
            pdA += __shfl_xor(pdA, off); pdB += __shfl_xor(pdB, off);
        }
        if (lr == 0) {
            int row = r0 + q * 4 + r;
            if (row < M) {
                al_src[(size_t)row * 4 + hb]     = psA;
                al_src[(size_t)row * 4 + hb + 1] = psB;
                al_dst[(size_t)row * 4 + hb]     = pdA;
                al_dst[(size_t)row * 4 + hb + 1] = pdB;
            }
        }
    }
}

// ---------------------------------------------------------------------------
// Layer-2 GEMM (MFMA): out = m16[M,128] @ W2 (via W2T[256,128]) + b2, fp32 out
// Block: 4 waves; wave w handles rows r0..r0+15, cols w*64..+63.
// ---------------------------------------------------------------------------
__global__ __launch_bounds__(256)
void gemm2_mfma(const __half* __restrict__ A16, const __half* __restrict__ W2T,
                const float* __restrict__ bias, float* __restrict__ out, int M)
{
    int wave = threadIdx.x >> 6, lane = threadIdx.x & 63;
    int lr = lane & 15, q = lane >> 4;
    int r0 = blockIdx.x * 16;
    int c0 = wave * 64;

    int arow = min(r0 + lr, M - 1);
    const uint4* Arow = (const uint4*)A16 + (size_t)arow * 16;
    half8 a[4];
#pragma unroll
    for (int kb = 0; kb < 4; ++kb) {
        union { uint4 u; half8 h; } c;
        c.u = Arow[kb * 4 + q];
        a[kb] = c.h;
    }

    floatx4 acc[4];
    const floatx4 zero = {0.f, 0.f, 0.f, 0.f};
#pragma unroll
    for (int ct = 0; ct < 4; ++ct) acc[ct] = zero;

#pragma unroll
    for (int ct = 0; ct < 4; ++ct) {
        const uint4* Brow = (const uint4*)W2T + (size_t)(c0 + ct * 16 + lr) * 16;
#pragma unroll
        for (int kb = 0; kb < 4; ++kb) {
            union { uint4 u; half8 h; } c;
            c.u = Brow[kb * 4 + q];
            acc[ct] = __builtin_amdgcn_mfma_f32_16x16x32_f16(a[kb], c.h, acc[ct], 0, 0, 0);
        }
    }

#pragma unroll
    for (int ct = 0; ct < 4; ++ct) {
        int col = c0 + ct * 16 + lr;
        float b = bias[col];
#pragma unroll
        for (int r = 0; r < 4; ++r) {
            int row = r0 + q * 4 + r;
            if (row < M) out[(size_t)row * 256 + col] = acc[ct][r] + b;
        }
    }
}

// ---------------------------------------------------------------------------
// Layer-1 aggregation, WAVE-PER-NODE (C=128 fp16, H=4). No LDS, no barriers.
// ---------------------------------------------------------------------------
__global__ __launch_bounds__(256)
void agg1_kernel(const __half* __restrict__ feat, const unsigned short* __restrict__ csr_src,
                 const int* __restrict__ offs, const float* __restrict__ alS,
                 const float* __restrict__ alD, const float* __restrict__ bias,
                 const float* __restrict__ w2s, const float* __restrict__ w2d,
                 __half* __restrict__ hmid, float* __restrict__ alS2,
                 float* __restrict__ alD2, int N)
{
    int lane = threadIdx.x & 63;
    int n = blockIdx.x * 4 + (threadIdx.x >> 6);
    if (n >= N) return;

    int lc = lane & 15;      // channel group: channels lc*8 .. lc*8+7
    int es = lane >> 4;      // edge slot 0..3
    int h = lc >> 2;         // head of this lane's channels

    float aD = alD[(size_t)n * 4 + h];
    int beg = offs[n], end = offs[n + 1];

    float acc0[8] = {0,0,0,0,0,0,0,0}, acc1[8] = {0,0,0,0,0,0,0,0};
    float sw0 = 0.f, sw1 = 0.f;
    const uint4* feat16 = (const uint4*)feat;

    int j = beg + es;
    for (; j + 4 < end; j += 8) {
        int s0 = csr_src[j];
        int s1 = csr_src[j + 4];
        float w0 = __expf(lrelu(alS[(size_t)s0 * 4 + h] + aD));
        float w1 = __expf(lrelu(alS[(size_t)s1 * 4 + h] + aD));
        uint4 f0 = feat16[(size_t)s0 * 16 + lc];
        uint4 f1 = feat16[(size_t)s1 * 16 + lc];
        fma8h(acc0, w0, f0); sw0 += w0;
        fma8h(acc1, w1, f1); sw1 += w1;
    }
    if (j < end) {
        int s0 = csr_src[j];
        float w0 = __expf(lrelu(alS[(size_t)s0 * 4 + h] + aD));
        uint4 f0 = feat16[(size_t)s0 * 16 + lc];
        fma8h(acc0, w0, f0); sw0 += w0;
    }

    float sw = sw0 + sw1;
    sw += __shfl_xor(sw, 16); sw += __shfl_xor(sw, 32);
#pragma unroll
    for (int i = 0; i < 8; ++i) {
        acc0[i] += acc1[i];
        acc0[i] += __shfl_xor(acc0[i], 16);
        acc0[i] += __shfl_xor(acc0[i], 32);
    }

    if (lane < 16) {
        float inv = 1.f / (sw + 1e-16f);
        float v[8];
#pragma unroll
        for (int i = 0; i < 8; ++i)
            v[i] = fmaxf(fmaf(acc0[i], inv, bias[lc * 8 + i]), 0.f);
        __half2 p0 = __floats2half2_rn(v[0], v[1]);
        __half2 p1 = __floats2half2_rn(v[2], v[3]);
        __half2 p2 = __floats2half2_rn(v[4], v[5]);
        __half2 p3 = __floats2half2_rn(v[6], v[7]);
        uint4 pk = make_uint4(*(unsigned*)&p0, *(unsigned*)&p1,
                              *(unsigned*)&p2, *(unsigned*)&p3);
        ((uint4*)hmid)[(size_t)n * 16 + lc] = pk;
        float ps = 0.f, pd = 0.f;
#pragma unroll
        for (int i = 0; i < 8; ++i) {
            ps = fmaf(v[i], w2s[lc * 8 + i], ps);
            pd = fmaf(v[i], w2d[lc * 8 + i], pd);
        }
        ps += __shfl_xor(ps, 1); ps += __shfl_xor(ps, 2);
        ps += __shfl_xor(ps, 4); ps += __shfl_xor(ps, 8);
        pd += __shfl_xor(pd, 1); pd += __shfl_xor(pd, 2);
        pd += __shfl_xor(pd, 4); pd += __shfl_xor(pd, 8);
        if (lane == 0) { alS2[n] = ps; alD2[n] = pd; }
    }
}

// ---------------------------------------------------------------------------
// Layer-2 aggregation, WAVE-PER-NODE, pre-projection (C=128 fp16, H=1).
// Outputs m in fp16 (GEMM2 MFMA input).
// ---------------------------------------------------------------------------
__global__ __launch_bounds__(256)
void agg2_kernel(const __half* __restrict__ feat, const unsigned short* __restrict__ csr_src,
                 const int* __restrict__ offs, const float* __restrict__ alS,
                 const float* __restrict__ alD, __half* __restrict__ m16, int N)
{
    int lane = threadIdx.x & 63;
    int n = blockIdx.x * 4 + (threadIdx.x >> 6);
    if (n >= N) return;

    int lc = lane & 15;
    int es = lane >> 4;

    float aD = alD[n];
    int beg = offs[n], end = offs[n + 1];

    float acc0[8] = {0,0,0,0,0,0,0,0}, acc1[8] = {0,0,0,0,0,0,0,0};
    float sw0 = 0.f, sw1 = 0.f;
    const uint4* feat16 = (const uint4*)feat;

    int j = beg + es;
    for (; j + 4 < end; j += 8) {
        int s0 = csr_src[j];
        int s1 = csr_src[j + 4];
        float w0 = __expf(lrelu(alS[s0] + aD));
        float w1 = __expf(lrelu(alS[s1] + aD));
        uint4 f0 = feat16[(size_t)s0 * 16 + lc];
        uint4 f1 = feat16[(size_t)s1 * 16 + lc];
        fma8h(acc0, w0, f0); sw0 += w0;
        fma8h(acc1, w1, f1); sw1 += w1;
    }
    if (j < end) {
        int s0 = csr_src[j];
        float w0 = __expf(lrelu(alS[s0] + aD));
        uint4 f0 = feat16[(size_t)s0 * 16 + lc];
        fma8h(acc0, w0, f0); sw0 += w0;
    }

    float sw = sw0 + sw1;
    sw += __shfl_xor(sw, 16); sw += __shfl_xor(sw, 32);
#pragma unroll
    for (int i = 0; i < 8; ++i) {
        acc0[i] += acc1[i];
        acc0[i] += __shfl_xor(acc0[i], 16);
        acc0[i] += __shfl_xor(acc0[i], 32);
    }

    if (lane < 16) {
        float inv = 1.f / (sw + 1e-16f);
        float v[8];
#pragma unroll
        for (int i = 0; i < 8; ++i) v[i] = acc0[i] * inv;
        __half2 p0 = __floats2half2_rn(v[0], v[1]);
        __half2 p1 = __floats2half2_rn(v[2], v[3]);
        __half2 p2 = __floats2half2_rn(v[4], v[5]);
        __half2 p3 = __floats2half2_rn(v[6], v[7]);
        uint4 pk = make_uint4(*(unsigned*)&p0, *(unsigned*)&p1,
                              *(unsigned*)&p2, *(unsigned*)&p3);
        ((uint4*)m16)[(size_t)n * 16 + lc] = pk;
    }
}

// ---------------------------------------------------------------------------
extern "C" void kernel_launch(void* const* d_in, const int* in_sizes, int n_in,
                              void* d_out, int out_size, void* d_ws, size_t ws_size,
                              hipStream_t stream)
{
    const float* x      = (const float*)d_in[0];
    const int*   ei     = (const int*)d_in[1];
    const float* W1     = (const float*)d_in[2];
    const float* a_src1 = (const float*)d_in[3];
    const float* a_dst1 = (const float*)d_in[4];
    const float* b1     = (const float*)d_in[5];
    const float* W2     = (const float*)d_in[6];
    const float* a_src2 = (const float*)d_in[7];
    const float* a_dst2 = (const float*)d_in[8];
    const float* b2     = (const float*)d_in[9];

    const int N    = in_sizes[0] / 128;
    const int E    = in_sizes[1] / 2;
    const int Etot = E + N;
    const int* src = ei;
    const int* dst = ei + E;
    const int nb   = (N + 127) >> 7;

    char* ws = (char*)d_ws;
    size_t off = 0;
    auto carve = [&](size_t bytes) -> void* {
        void* p = ws + off;
        off += (bytes + 255) & ~(size_t)255;
        return p;
    };
    __half*  x16  = (__half*)carve((size_t)N * 128 * 2);
    __half*  h1   = (__half*)carve((size_t)N * 128 * 2);
    __half*  hmid = (__half*)carve((size_t)N * 128 * 2);
    __half*  m16  = (__half*)carve((size_t)N * 128 * 2);
    __half*  W1T  = (__half*)carve(128 * 128 * 2);
    __half*  W2T  = (__half*)carve(256 * 128 * 2);
    float*   alS1 = (float*)carve((size_t)N * 4 * 4);
    float*   alD1 = (float*)carve((size_t)N * 4 * 4);
    float*   alS2 = (float*)carve((size_t)N * 4);
    float*   alD2 = (float*)carve((size_t)N * 4);
    float*   w2s  = (float*)carve(128 * 4);
    float*   w2d  = (float*)carve(128 * 4);
    int*     offs = (int*)carve((size_t)(N + 1) * 4);
    int*     bcnt = (int*)carve(512 * 4);
    int*     bbas = (int*)carve(512 * 4);
    int*     gcur = (int*)carve(512 * 4);
    unsigned* eout = (unsigned*)carve((size_t)Etot * 4);
    unsigned short* csr = (unsigned short*)carve((size_t)Etot * 2);
    (void)ws_size; (void)n_in; (void)out_size;

    const int TB = 256;
    const int agrid = (N + 3) / 4;     // wave-per-node agg blocks
    const int g1grid = (N + 31) / 32;  // gemm1: 32 rows/block
    const int g2grid = (N + 15) / 16;  // gemm2: 16 rows/block
    const int nx = N * 128;

    hipMemsetAsync(bcnt, 0, 512 * 4, stream);

    // CSR build (counting sort, coalesced writes)
    bucketA_kernel<<<512, TB, 0, stream>>>(src, dst, bcnt, E, Etot, nb);
    scanBuckets_kernel<<<1, 512, 0, stream>>>(bcnt, bbas, gcur, nb, offs, N, Etot);
    bucketB_kernel<<<(Etot + BE - 1) / BE, TB, 0, stream>>>(src, dst, gcur, eout, E, Etot, nb);
    bucketC_kernel<<<nb, TB, 0, stream>>>(eout, bbas, bcnt, csr, offs, N);

    // Precompute: fp16 casts, transposed weights, fused-al2 vectors
    cast_f2h_kernel<<<(nx / 4 + TB - 1) / TB, TB, 0, stream>>>(x, x16, nx);
    transposeW_kernel<<<128, 128, 0, stream>>>(W1, W1T, 128);
    transposeW_kernel<<<256, 128, 0, stream>>>(W2, W2T, 256);
    w2sd_kernel<<<1, 256, 0, stream>>>(W2, a_src2, a_dst2, w2s, w2d);

    // Layer 1
    gemm1_mfma<<<g1grid, 256, 0, stream>>>(x16, W1T, a_src1, a_dst1, h1, alS1, alD1, N);
    agg1_kernel<<<agrid, 256, 0, stream>>>(h1, csr, offs, alS1, alD1, b1,
                                           w2s, w2d, hmid, alS2, alD2, N);

    // Layer 2: aggregate in 128-dim pre-projection space, then MFMA GEMM
    agg2_kernel<<<agrid, 256, 0, stream>>>(hmid, csr, offs, alS2, alD2, m16, N);
    gemm2_mfma<<<g2grid, 256, 0, stream>>>(m16, W2T, b2, (float*)d_out, N);
}

// Round 8
// 305.941 us; speedup vs baseline: 1.4909x; 1.0812x over previous
//
#include <hip/hip_runtime.h>
#include <hip/hip_fp16.h>
#include <math.h>

#define NSLOPE 0.2f

typedef _Float16 half8 __attribute__((ext_vector_type(8)));
typedef float floatx4 __attribute__((ext_vector_type(4)));

__device__ __forceinline__ float lrelu(float t) { return t > 0.f ? t : NSLOPE * t; }

// accumulate 8 fp16 values (packed in uint4) scaled by w into acc[8]
__device__ __forceinline__ void fma8h(float* acc, float w, const uint4& v) {
    const __half2* h2 = reinterpret_cast<const __half2*>(&v);
#pragma unroll
    for (int i = 0; i < 4; ++i) {
        float2 f = __half22float2(h2[i]);
        acc[2 * i]     = fmaf(w, f.x, acc[2 * i]);
        acc[2 * i + 1] = fmaf(w, f.y, acc[2 * i + 1]);
    }
}

#define MAXB 5632
#define BE   8192

// ---------------------------------------------------------------------------
// PREP combo kernel: independent setup work in ONE dispatch.
//   blocks [0, nbA)                : bucketA  (dst-bucket histogram)
//   blocks [nbA, nbA+ncast)        : cast x fp32 -> fp16
//   blocks [.., +nt1)              : W1T transpose (fp16)
//   blocks [.., +nt2)              : W2T transpose (fp16)
//   last block                     : w2s/w2d = W2 @ a_src2 / a_dst2
// ---------------------------------------------------------------------------
__global__ __launch_bounds__(256)
void prep_kernel(const int* __restrict__ dst, int* __restrict__ bcnt,
                 const float* __restrict__ x, __half* __restrict__ x16, int nx,
                 const float* __restrict__ W1, __half* __restrict__ W1T,
                 const float* __restrict__ W2, __half* __restrict__ W2T,
                 const float* __restrict__ a_src2, const float* __restrict__ a_dst2,
                 float* __restrict__ w2s, float* __restrict__ w2d,
                 int E, int Etot, int nb, int nbA, int ncast, int nt1, int nt2)
{
    __shared__ int hist[512];
    int bid = blockIdx.x;
    int tid = threadIdx.x;

    if (bid < nbA) {
        // ---- bucketA: histogram of dst>>7 ----
        for (int i = tid; i < 512; i += 256) hist[i] = 0;
        __syncthreads();
        for (int e = bid * 256 + tid; e < Etot; e += nbA * 256) {
            int d = (e < E) ? dst[e] : (e - E);
            atomicAdd(&hist[d >> 7], 1);
        }
        __syncthreads();
        for (int i = tid; i < nb; i += 256) {
            int v = hist[i];
            if (v) atomicAdd(&bcnt[i], v);
        }
        return;
    }
    bid -= nbA;
    if (bid < ncast) {
        int i = (bid * 256 + tid) * 4;
        if (i < nx) {
            float4 v = *(const float4*)&x[i];
            __half2 a = __floats2half2_rn(v.x, v.y);
            __half2 b = __floats2half2_rn(v.z, v.w);
            *(uint2*)&x16[i] = make_uint2(*(unsigned*)&a, *(unsigned*)&b);
        }
        return;
    }
    bid -= ncast;
    if (bid < nt1) {
        int idx = bid * 256 + tid;       // 128x128
        int c = idx >> 7, k = idx & 127;
        W1T[(size_t)c * 128 + k] = __float2half(W1[(size_t)k * 128 + c]);
        return;
    }
    bid -= nt1;
    if (bid < nt2) {
        int idx = bid * 256 + tid;       // 256x128
        int c = idx >> 7, k = idx & 127;
        W2T[(size_t)c * 128 + k] = __float2half(W2[(size_t)k * 256 + c]);
        return;
    }
    // ---- w2sd ----
    {
        const float* a = (tid < 128) ? a_src2 : a_dst2;
        int k = tid & 127;
        float acc = 0.f;
        for (int c = 0; c < 256; c += 4) {
            float4 w = *(const float4*)&W2[(size_t)k * 256 + c];
            float4 av = *(const float4*)&a[c];
            acc = fmaf(w.x, av.x, fmaf(w.y, av.y, fmaf(w.z, av.z, fmaf(w.w, av.w, acc))));
        }
        if (tid < 128) w2s[k] = acc; else w2d[k] = acc;
    }
}

// ---------------------------------------------------------------------------
// scan of bucket counts (1 block)
// ---------------------------------------------------------------------------
__global__ __launch_bounds__(512)
void scanBuckets_kernel(const int* __restrict__ bcnt, int* __restrict__ bbase,
                        int* __restrict__ gcur, int nb, int* __restrict__ offs,
                        int N, int total)
{
    __shared__ int tmp[512];
    int tid = threadIdx.x;
    int v = (tid < nb) ? bcnt[tid] : 0;
    tmp[tid] = v;
    __syncthreads();
    for (int off = 1; off < 512; off <<= 1) {
        int t = (tid >= off) ? tmp[tid - off] : 0;
        __syncthreads();
        tmp[tid] += t;
        __syncthreads();
    }
    if (tid < nb) {
        int e = tmp[tid] - v;
        bbase[tid] = e;
        gcur[tid] = e;
    }
    if (tid == 0) offs[N] = total;
}

// ---------------------------------------------------------------------------
// bucketB: partition edges into bucket-grouped u32 records src | (dst&127)<<16
// ---------------------------------------------------------------------------
__global__ __launch_bounds__(256)
void bucketB_kernel(const int* __restrict__ src, const int* __restrict__ dst,
                    int* __restrict__ gcur, unsigned* __restrict__ eout,
                    int E, int Etot, int nb)
{
    __shared__ int hist[512];
    __shared__ int res[512];
    __shared__ int lcur[512];
    int tid = threadIdx.x;
    int e0 = blockIdx.x * BE;
    int e1 = min(e0 + BE, Etot);

    for (int i = tid; i < 512; i += 256) hist[i] = 0;
    __syncthreads();
    for (int e = e0 + tid; e < e1; e += 256) {
        int d = (e < E) ? dst[e] : (e - E);
        atomicAdd(&hist[d >> 7], 1);
    }
    __syncthreads();
    for (int i = tid; i < nb; i += 256) {
        int h = hist[i];
        res[i] = h ? atomicAdd(&gcur[i], h) : 0;
        lcur[i] = 0;
    }
    __syncthreads();
    for (int e = e0 + tid; e < e1; e += 256) {
        int s, d;
        if (e < E) { s = src[e]; d = dst[e]; }
        else       { s = e - E; d = s; }
        int b = d >> 7;
        int p = res[b] + atomicAdd(&lcur[b], 1);
        eout[p] = (unsigned)s | ((unsigned)(d & 127) << 16);
    }
}

// ---------------------------------------------------------------------------
// COMBO kernel: bucketC (in-LDS sub-CSR) for blocks [0,nb); gemm1 (MFMA) after.
// Both only depend on earlier dispatches; blocks are independent.
// ---------------------------------------------------------------------------
__global__ __launch_bounds__(256)
void combo_kernel(const unsigned* __restrict__ eout, const int* __restrict__ bbase,
                  const int* __restrict__ bcnt, unsigned short* __restrict__ csr,
                  int* __restrict__ offs, int N, int nb,
                  const __half* __restrict__ A16, const __half* __restrict__ W1T,
                  const float* __restrict__ a_src, const float* __restrict__ a_dst,
                  __half* __restrict__ h1, float* __restrict__ al_src,
                  float* __restrict__ al_dst)
{
    __shared__ unsigned eb[MAXB];
    __shared__ unsigned short sbuf[MAXB];
    __shared__ int cnt128[128], cur128[128], sc[128];

    int tid = threadIdx.x;
    if ((int)blockIdx.x < nb) {
        // ---------------- bucketC ----------------
        int b = blockIdx.x;
        int ebase = bbase[b];
        int ecnt = bcnt[b];
        int n0 = b << 7;
        int ncount = min(128, N - n0);

        if (tid < 128) cnt128[tid] = 0;
        for (int i = tid; i < ecnt; i += 256) eb[i] = eout[ebase + i];
        __syncthreads();
        for (int i = tid; i < ecnt; i += 256) atomicAdd(&cnt128[eb[i] >> 16], 1);
        __syncthreads();
        if (tid < 128) sc[tid] = cnt128[tid];
        __syncthreads();
        for (int off = 1; off < 128; off <<= 1) {
            int t = (tid >= off && tid < 128) ? sc[tid - off] : 0;
            __syncthreads();
            if (tid < 128) sc[tid] += t;
            __syncthreads();
        }
        if (tid < 128) {
            int excl = sc[tid] - cnt128[tid];
            cur128[tid] = excl;
            if (tid < ncount) offs[n0 + tid] = ebase + excl;
        }
        __syncthreads();
        for (int i = tid; i < ecnt; i += 256) {
            unsigned v = eb[i];
            int p = atomicAdd(&cur128[v >> 16], 1);
            sbuf[p] = (unsigned short)(v & 0xFFFFu);
        }
        __syncthreads();
        for (int i = tid; i < ecnt; i += 256) csr[ebase + i] = sbuf[i];
        return;
    }

    // ---------------- gemm1 (MFMA) ----------------
    int gb = blockIdx.x - nb;
    int M = N;
    int wave = tid >> 6, lane = tid & 63;
    int lr = lane & 15, q = lane >> 4;
    int r0 = gb * 32 + (wave >> 1) * 16;
    int wcol = (wave & 1) * 64;

    int arow = min(r0 + lr, M - 1);
    const uint4* Arow = (const uint4*)A16 + (size_t)arow * 16;
    half8 a[4];
#pragma unroll
    for (int kb = 0; kb < 4; ++kb) {
        union { uint4 u; half8 h; } c;
        c.u = Arow[kb * 4 + q];
        a[kb] = c.h;
    }

    floatx4 acc[4];
    const floatx4 zero = {0.f, 0.f, 0.f, 0.f};
#pragma unroll
    for (int ct = 0; ct < 4; ++ct) acc[ct] = zero;

#pragma unroll
    for (int ct = 0; ct < 4; ++ct) {
        const uint4* Brow = (const uint4*)W1T + (size_t)(wcol + ct * 16 + lr) * 16;
#pragma unroll
        for (int kb = 0; kb < 4; ++kb) {
            union { uint4 u; half8 h; } c;
            c.u = Brow[kb * 4 + q];
            acc[ct] = __builtin_amdgcn_mfma_f32_16x16x32_f16(a[kb], c.h, acc[ct], 0, 0, 0);
        }
    }

#pragma unroll
    for (int ct = 0; ct < 4; ++ct) {
        int col = wcol + ct * 16 + lr;
#pragma unroll
        for (int r = 0; r < 4; ++r) {
            int row = r0 + q * 4 + r;
            if (row < M) h1[(size_t)row * 128 + col] = __float2half(acc[ct][r]);
        }
    }

    float as[4], ad[4];
#pragma unroll
    for (int ct = 0; ct < 4; ++ct) {
        int col = wcol + ct * 16 + lr;
        as[ct] = a_src[col];
        ad[ct] = a_dst[col];
    }
    int hb = wcol >> 5;
#pragma unroll
    for (int r = 0; r < 4; ++r) {
        float psA = acc[0][r] * as[0] + acc[1][r] * as[1];
        float psB = acc[2][r] * as[2] + acc[3][r] * as[3];
        float pdA = acc[0][r] * ad[0] + acc[1][r] * ad[1];
        float pdB = acc[2][r] * ad[2] + acc[3][r] * ad[3];
#pragma unroll
        for (int off = 1; off < 16; off <<= 1) {
            psA += __shfl_xor(psA, off); psB += __shfl_xor(psB, off);
            pdA += __shfl_xor(pdA, off); pdB += __shfl_xor(pdB, off);
        }
        if (lr == 0) {
            int row = r0 + q * 4 + r;
            if (row < M) {
                al_src[(size_t)row * 4 + hb]     = psA;
                al_src[(size_t)row * 4 + hb + 1] = psB;
                al_dst[(size_t)row * 4 + hb]     = pdA;
                al_dst[(size_t)row * 4 + hb + 1] = pdB;
            }
        }
    }
}

// ---------------------------------------------------------------------------
// Layer-2 GEMM (MFMA): out = m16[M,128] @ W2 (via W2T[256,128]) + b2, fp32 out
// ---------------------------------------------------------------------------
__global__ __launch_bounds__(256)
void gemm2_mfma(const __half* __restrict__ A16, const __half* __restrict__ W2T,
                const float* __restrict__ bias, float* __restrict__ out, int M)
{
    int wave = threadIdx.x >> 6, lane = threadIdx.x & 63;
    int lr = lane & 15, q = lane >> 4;
    int r0 = blockIdx.x * 16;
    int c0 = wave * 64;

    int arow = min(r0 + lr, M - 1);
    const uint4* Arow = (const uint4*)A16 + (size_t)arow * 16;
    half8 a[4];
#pragma unroll
    for (int kb = 0; kb < 4; ++kb) {
        union { uint4 u; half8 h; } c;
        c.u = Arow[kb * 4 + q];
        a[kb] = c.h;
    }

    floatx4 acc[4];
    const floatx4 zero = {0.f, 0.f, 0.f, 0.f};
#pragma unroll
    for (int ct = 0; ct < 4; ++ct) acc[ct] = zero;

#pragma unroll
    for (int ct = 0; ct < 4; ++ct) {
        const uint4* Brow = (const uint4*)W2T + (size_t)(c0 + ct * 16 + lr) * 16;
#pragma unroll
        for (int kb = 0; kb < 4; ++kb) {
            union { uint4 u; half8 h; } c;
            c.u = Brow[kb * 4 + q];
            acc[ct] = __builtin_amdgcn_mfma_f32_16x16x32_f16(a[kb], c.h, acc[ct], 0, 0, 0);
        }
    }

#pragma unroll
    for (int ct = 0; ct < 4; ++ct) {
        int col = c0 + ct * 16 + lr;
        float b = bias[col];
#pragma unroll
        for (int r = 0; r < 4; ++r) {
            int row = r0 + q * 4 + r;
            if (row < M) out[(size_t)row * 256 + col] = acc[ct][r] + b;
        }
    }
}

// ---------------------------------------------------------------------------
// Layer-1 aggregation, WAVE-PER-NODE (C=128 fp16, H=4). No LDS, no barriers.
// ---------------------------------------------------------------------------
__global__ __launch_bounds__(256)
void agg1_kernel(const __half* __restrict__ feat, const unsigned short* __restrict__ csr_src,
                 const int* __restrict__ offs, const float* __restrict__ alS,
                 const float* __restrict__ alD, const float* __restrict__ bias,
                 const float* __restrict__ w2s, const float* __restrict__ w2d,
                 __half* __restrict__ hmid, float* __restrict__ alS2,
                 float* __restrict__ alD2, int N)
{
    int lane = threadIdx.x & 63;
    int n = blockIdx.x * 4 + (threadIdx.x >> 6);
    if (n >= N) return;

    int lc = lane & 15;      // channel group: channels lc*8 .. lc*8+7
    int es = lane >> 4;      // edge slot 0..3
    int h = lc >> 2;         // head of this lane's channels

    float aD = alD[(size_t)n * 4 + h];
    int beg = offs[n], end = offs[n + 1];

    float acc0[8] = {0,0,0,0,0,0,0,0}, acc1[8] = {0,0,0,0,0,0,0,0};
    float sw0 = 0.f, sw1 = 0.f;
    const char* fbase = (const char*)feat + lc * 16;

    int j = beg + es;
    for (; j + 4 < end; j += 8) {
        int s0 = csr_src[j];
        int s1 = csr_src[j + 4];
        float w0 = __expf(lrelu(alS[(size_t)s0 * 4 + h] + aD));
        float w1 = __expf(lrelu(alS[(size_t)s1 * 4 + h] + aD));
        uint4 f0 = *(const uint4*)(fbase + (size_t)s0 * 256);
        uint4 f1 = *(const uint4*)(fbase + (size_t)s1 * 256);
        fma8h(acc0, w0, f0); sw0 += w0;
        fma8h(acc1, w1, f1); sw1 += w1;
    }
    if (j < end) {
        int s0 = csr_src[j];
        float w0 = __expf(lrelu(alS[(size_t)s0 * 4 + h] + aD));
        uint4 f0 = *(const uint4*)(fbase + (size_t)s0 * 256);
        fma8h(acc0, w0, f0); sw0 += w0;
    }

    float sw = sw0 + sw1;
    sw += __shfl_xor(sw, 16); sw += __shfl_xor(sw, 32);
#pragma unroll
    for (int i = 0; i < 8; ++i) {
        acc0[i] += acc1[i];
        acc0[i] += __shfl_xor(acc0[i], 16);
        acc0[i] += __shfl_xor(acc0[i], 32);
    }

    if (lane < 16) {
        float inv = 1.f / (sw + 1e-16f);
        float v[8];
#pragma unroll
        for (int i = 0; i < 8; ++i)
            v[i] = fmaxf(fmaf(acc0[i], inv, bias[lc * 8 + i]), 0.f);
        __half2 p0 = __floats2half2_rn(v[0], v[1]);
        __half2 p1 = __floats2half2_rn(v[2], v[3]);
        __half2 p2 = __floats2half2_rn(v[4], v[5]);
        __half2 p3 = __floats2half2_rn(v[6], v[7]);
        uint4 pk = make_uint4(*(unsigned*)&p0, *(unsigned*)&p1,
                              *(unsigned*)&p2, *(unsigned*)&p3);
        ((uint4*)hmid)[(size_t)n * 16 + lc] = pk;
        float ps = 0.f, pd = 0.f;
#pragma unroll
        for (int i = 0; i < 8; ++i) {
            ps = fmaf(v[i], w2s[lc * 8 + i], ps);
            pd = fmaf(v[i], w2d[lc * 8 + i], pd);
        }
        ps += __shfl_xor(ps, 1); ps += __shfl_xor(ps, 2);
        ps += __shfl_xor(ps, 4); ps += __shfl_xor(ps, 8);
        pd += __shfl_xor(pd, 1); pd += __shfl_xor(pd, 2);
        pd += __shfl_xor(pd, 4); pd += __shfl_xor(pd, 8);
        if (lane == 0) { alS2[n] = ps; alD2[n] = pd; }
    }
}

// ---------------------------------------------------------------------------
// Layer-2 aggregation, WAVE-PER-NODE, pre-projection (C=128 fp16, H=1).
// ---------------------------------------------------------------------------
__global__ __launch_bounds__(256)
void agg2_kernel(const __half* __restrict__ feat, const unsigned short* __restrict__ csr_src,
                 const int* __restrict__ offs, const float* __restrict__ alS,
                 const float* __restrict__ alD, __half* __restrict__ m16, int N)
{
    int lane = threadIdx.x & 63;
    int n = blockIdx.x * 4 + (threadIdx.x >> 6);
    if (n >= N) return;

    int lc = lane & 15;
    int es = lane >> 4;

    float aD = alD[n];
    int beg = offs[n], end = offs[n + 1];

    float acc0[8] = {0,0,0,0,0,0,0,0}, acc1[8] = {0,0,0,0,0,0,0,0};
    float sw0 = 0.f, sw1 = 0.f;
    const char* fbase = (const char*)feat + lc * 16;

    int j = beg + es;
    for (; j + 4 < end; j += 8) {
        int s0 = csr_src[j];
        int s1 = csr_src[j + 4];
        float w0 = __expf(lrelu(alS[s0] + aD));
        float w1 = __expf(lrelu(alS[s1] + aD));
        uint4 f0 = *(const uint4*)(fbase + (size_t)s0 * 256);
        uint4 f1 = *(const uint4*)(fbase + (size_t)s1 * 256);
        fma8h(acc0, w0, f0); sw0 += w0;
        fma8h(acc1, w1, f1); sw1 += w1;
    }
    if (j < end) {
        int s0 = csr_src[j];
        float w0 = __expf(lrelu(alS[s0] + aD));
        uint4 f0 = *(const uint4*)(fbase + (size_t)s0 * 256);
        fma8h(acc0, w0, f0); sw0 += w0;
    }

    float sw = sw0 + sw1;
    sw += __shfl_xor(sw, 16); sw += __shfl_xor(sw, 32);
#pragma unroll
    for (int i = 0; i < 8; ++i) {
        acc0[i] += acc1[i];
        acc0[i] += __shfl_xor(acc0[i], 16);
        acc0[i] += __shfl_xor(acc0[i], 32);
    }

    if (lane < 16) {
        float inv = 1.f / (sw + 1e-16f);
        float v[8];
#pragma unroll
        for (int i = 0; i < 8; ++i) v[i] = acc0[i] * inv;
        __half2 p0 = __floats2half2_rn(v[0], v[1]);
        __half2 p1 = __floats2half2_rn(v[2], v[3]);
        __half2 p2 = __floats2half2_rn(v[4], v[5]);
        __half2 p3 = __floats2half2_rn(v[6], v[7]);
        uint4 pk = make_uint4(*(unsigned*)&p0, *(unsigned*)&p1,
                              *(unsigned*)&p2, *(unsigned*)&p3);
        ((uint4*)m16)[(size_t)n * 16 + lc] = pk;
    }
}

// ---------------------------------------------------------------------------
extern "C" void kernel_launch(void* const* d_in, const int* in_sizes, int n_in,
                              void* d_out, int out_size, void* d_ws, size_t ws_size,
                              hipStream_t stream)
{
    const float* x      = (const float*)d_in[0];
    const int*   ei     = (const int*)d_in[1];
    const float* W1     = (const float*)d_in[2];
    const float* a_src1 = (const float*)d_in[3];
    const float* a_dst1 = (const float*)d_in[4];
    const float* b1     = (const float*)d_in[5];
    const float* W2     = (const float*)d_in[6];
    const float* a_src2 = (const float*)d_in[7];
    const float* a_dst2 = (const float*)d_in[8];
    const float* b2     = (const float*)d_in[9];

    const int N    = in_sizes[0] / 128;
    const int E    = in_sizes[1] / 2;
    const int Etot = E + N;
    const int* src = ei;
    const int* dst = ei + E;
    const int nb   = (N + 127) >> 7;

    char* ws = (char*)d_ws;
    size_t off = 0;
    auto carve = [&](size_t bytes) -> void* {
        void* p = ws + off;
        off += (bytes + 255) & ~(size_t)255;
        return p;
    };
    __half*  x16  = (__half*)carve((size_t)N * 128 * 2);
    __half*  h1   = (__half*)carve((size_t)N * 128 * 2);
    __half*  hmid = (__half*)carve((size_t)N * 128 * 2);
    __half*  m16  = (__half*)carve((size_t)N * 128 * 2);
    __half*  W1T  = (__half*)carve(128 * 128 * 2);
    __half*  W2T  = (__half*)carve(256 * 128 * 2);
    float*   alS1 = (float*)carve((size_t)N * 4 * 4);
    float*   alD1 = (float*)carve((size_t)N * 4 * 4);
    float*   alS2 = (float*)carve((size_t)N * 4);
    float*   alD2 = (float*)carve((size_t)N * 4);
    float*   w2s  = (float*)carve(128 * 4);
    float*   w2d  = (float*)carve(128 * 4);
    int*     offs = (int*)carve((size_t)(N + 1) * 4);
    int*     bcnt = (int*)carve(512 * 4);
    int*     bbas = (int*)carve(512 * 4);
    int*     gcur = (int*)carve(512 * 4);
    unsigned* eout = (unsigned*)carve((size_t)Etot * 4);
    unsigned short* csr = (unsigned short*)carve((size_t)Etot * 2);
    (void)ws_size; (void)n_in; (void)out_size;

    const int TB = 256;
    const int agrid = (N + 3) / 4;     // wave-per-node agg blocks
    const int g1grid = (N + 31) / 32;  // gemm1: 32 rows/block
    const int g2grid = (N + 15) / 16;  // gemm2: 16 rows/block
    const int nx = N * 128;

    // prep combo block ranges
    const int nbA   = 512;
    const int ncast = (nx / 4 + TB - 1) / TB;
    const int nt1   = (128 * 128 + TB - 1) / TB;
    const int nt2   = (256 * 128 + TB - 1) / TB;
    const int nprep = nbA + ncast + nt1 + nt2 + 1;

    hipMemsetAsync(bcnt, 0, 512 * 4, stream);

    // 1. prep: bucketA + cast + transposes + w2sd (all independent)
    prep_kernel<<<nprep, TB, 0, stream>>>(dst, bcnt, x, x16, nx, W1, W1T, W2, W2T,
                                          a_src2, a_dst2, w2s, w2d,
                                          E, Etot, nb, nbA, ncast, nt1, nt2);
    // 2. bucket scan
    scanBuckets_kernel<<<1, 512, 0, stream>>>(bcnt, bbas, gcur, nb, offs, N, Etot);
    // 3. bucket partition
    bucketB_kernel<<<(Etot + BE - 1) / BE, TB, 0, stream>>>(src, dst, gcur, eout, E, Etot, nb);
    // 4. combo: bucketC (sub-CSR) + gemm1 (MFMA) — independent of each other
    combo_kernel<<<nb + g1grid, TB, 0, stream>>>(eout, bbas, bcnt, csr, offs, N, nb,
                                                 x16, W1T, a_src1, a_dst1, h1, alS1, alD1);
    // 5. layer-1 aggregation (+ fused al2 dots, hmid fp16)
    agg1_kernel<<<agrid, TB, 0, stream>>>(h1, csr, offs, alS1, alD1, b1,
                                          w2s, w2d, hmid, alS2, alD2, N);
    // 6. layer-2 aggregation in pre-projection space
    agg2_kernel<<<agrid, TB, 0, stream>>>(hmid, csr, offs, alS2, alD2, m16, N);
    // 7. layer-2 GEMM (MFMA) + bias
    gemm2_mfma<<<g2grid, TB, 0, stream>>>(m16, W2T, b2, (float*)d_out, N);
}